// Round 2
// baseline (786.997 us; speedup 1.0000x reference)
//
#include <hip/hip_runtime.h>

// RNN: B=512, T=1024, I=64, H=128, fp32 in/out.
// Round-5 structure: latency-bound recurrence -> remove ALL cross-lane
// reduction from the serial chain. NT=128 (2 waves), lane j = tid owns one
// full output unit over the whole K=192: W_hh[j][:] (64 half2) + W_ih[j][:]
// (32 half2) live in 96 VGPRs for the entire kernel.
//  - no __shfl/ds_bpermute in the recurrence (round-4 chain had 2 dependent
//    ds_bpermute ~100cy each per step)
//  - h exchange: ds_write_b16 per lane -> 2-wave barrier -> 16 uniform-
//    address ds_read_b128 (same-address broadcast = conflict-free)
//  - x-projection of step t+1 pipelined into the barrier shadow
//  - 512 blocks x 128 thr: 1 row/block, 2 blocks/CU overlap barrier stalls
// Precision: f16 weights/activations, fp32 accum via v_dot2 (unchanged).

#define Bsz 512
#define Tt  1024
#define Ii  64
#define Hh  128
constexpr int TC = 32;          // timesteps per LDS x-chunk
constexpr int NT = 128;         // threads per block (2 waves)

typedef _Float16 half2v __attribute__((ext_vector_type(2)));
typedef _Float16 half4v __attribute__((ext_vector_type(4)));
typedef _Float16 half8v __attribute__((ext_vector_type(8)));

union h8u { half8v v; half2v h[4]; };   // subregister aliasing, no insts

__device__ __forceinline__ float dot2(half2v a, half2v b, float c) {
#if __has_builtin(__builtin_amdgcn_fdot2)
    return __builtin_amdgcn_fdot2(a, b, c, false);
#else
    return c + (float)a[0] * (float)b[0] + (float)a[1] * (float)b[1];
#endif
}

__device__ __forceinline__ float fast_tanh(float x) {
    float t = __builtin_amdgcn_exp2f(x * 2.8853900817779268f);
    return 1.0f - 2.0f * __builtin_amdgcn_rcpf(t + 1.0f);
}
__device__ __forceinline__ float fast_sigmoid(float z) {
    float t = __builtin_amdgcn_exp2f(-z * 1.4426950408889634f);
    return __builtin_amdgcn_rcpf(1.0f + t);
}
__device__ __forceinline__ half4v cvt4(float4 p) {
    half4v r; r[0] = (_Float16)p.x; r[1] = (_Float16)p.y;
    r[2] = (_Float16)p.z; r[3] = (_Float16)p.w; return r;
}

__global__ __launch_bounds__(NT, 2)   // cap 256 VGPR, min 2 waves/EU
void rnn_rowwave(const float* __restrict__ x,
                 const float* __restrict__ W_ih,
                 const float* __restrict__ W_hh,
                 const float* __restrict__ b_ih,
                 const float* __restrict__ b_hh,
                 const float* __restrict__ fc_w,
                 const float* __restrict__ fc_b,
                 float* __restrict__ out)
{
    __shared__ __align__(16) _Float16 xs[2][TC * Ii];   // 2 x 4 KB f16 x chunks
    __shared__ __align__(16) _Float16 hb[2][Hh];        // ping-pong hidden, 2 x 256 B
    __shared__ float wred[2];

    const int tid = threadIdx.x;     // = hidden unit j (0..127)
    const int row = blockIdx.x;

    // ---- weights -> f16 registers: full K per lane, 96 half2 = 96 VGPRs ----
    half2v whh[64];                  // W_hh[j][0:128]
    {
        const float4* g = (const float4*)(W_hh + tid * Hh);
        #pragma unroll
        for (int k = 0; k < 32; ++k) {
            float4 v = g[k];
            whh[2*k][0]   = (_Float16)v.x; whh[2*k][1]   = (_Float16)v.y;
            whh[2*k+1][0] = (_Float16)v.z; whh[2*k+1][1] = (_Float16)v.w;
        }
    }
    half2v wih[32];                  // W_ih[j][0:64]
    {
        const float4* g = (const float4*)(W_ih + tid * Ii);
        #pragma unroll
        for (int k = 0; k < 16; ++k) {
            float4 v = g[k];
            wih[2*k][0]   = (_Float16)v.x; wih[2*k][1]   = (_Float16)v.y;
            wih[2*k+1][0] = (_Float16)v.z; wih[2*k+1][1] = (_Float16)v.w;
        }
    }
    const float bias = b_ih[tid] + b_hh[tid];
    const float fw   = fc_w[tid];

    if (tid < Hh / 2) ((half2v*)hb[0])[tid] = (half2v)0;   // h0 = 0

    // ---- x chunk prefetch: 4 float4/thread, stored as f16 ----
    const float4* xsrc = (const float4*)(x + (size_t)row * Tt * Ii);
    float4 p0 = xsrc[tid], p1 = xsrc[tid + NT], p2 = xsrc[tid + 2*NT], p3 = xsrc[tid + 3*NT];

    float hn = 0.0f;
    float fx0, fx1, fx2, fx3;        // pipelined x-projection chains

    // x-part of step TT: 32 dot2 over 8 uniform-address b128 reads
#define XP(TTv, CBv)                                                         \
    do {                                                                     \
        const h8u* xv = (const h8u*)(xs[CBv] + (TTv) * Ii);                  \
        fx0 = 0.f; fx1 = 0.f; fx2 = 0.f; fx3 = 0.f;                          \
        _Pragma("unroll")                                                    \
        for (int k = 0; k < 8; ++k) {                                        \
            h8u xq; xq.v = xv[k].v;                                          \
            fx0 = dot2(xq.h[0], wih[4*k    ], fx0);                          \
            fx1 = dot2(xq.h[1], wih[4*k + 1], fx1);                          \
            fx2 = dot2(xq.h[2], wih[4*k + 2], fx2);                          \
            fx3 = dot2(xq.h[3], wih[4*k + 3], fx3);                          \
        }                                                                    \
    } while (0)

    for (int t0 = 0; t0 < Tt; t0 += TC) {
        const int cb = (t0 / TC) & 1;
        ((half4v*)xs[cb])[tid]          = cvt4(p0);
        ((half4v*)xs[cb])[tid + NT]     = cvt4(p1);
        ((half4v*)xs[cb])[tid + 2*NT]   = cvt4(p2);
        ((half4v*)xs[cb])[tid + 3*NT]   = cvt4(p3);
        if (t0 + TC < Tt) {
            const int base = (t0 + TC) * (Ii / 4);
            p0 = xsrc[base + tid];        p1 = xsrc[base + tid + NT];
            p2 = xsrc[base + tid + 2*NT]; p3 = xsrc[base + tid + 3*NT];
        }
        __syncthreads();
        XP(0, cb);                       // x-part of first step of chunk

        #pragma unroll 2
        for (int tt = 0; tt < TC; ++tt) {
            const int p = tt & 1;
            // h_t broadcast: 16 uniform-address ds_read_b128 (conflict-free)
            const h8u* hv = (const h8u*)(hb[p]);
            float a0 = fx0, a1 = fx1, a2 = fx2, a3 = fx3;
            float a4 = 0.f, a5 = 0.f, a6 = 0.f, a7 = 0.f;
            #pragma unroll
            for (int k = 0; k < 16; ++k) {           // 64 dot2, 8 chains x 8 deep
                h8u hq; hq.v = hv[k].v;
                const int c = (k & 1) * 4;
                if (c == 0) {
                    a0 = dot2(hq.h[0], whh[4*k    ], a0);
                    a1 = dot2(hq.h[1], whh[4*k + 1], a1);
                    a2 = dot2(hq.h[2], whh[4*k + 2], a2);
                    a3 = dot2(hq.h[3], whh[4*k + 3], a3);
                } else {
                    a4 = dot2(hq.h[0], whh[4*k    ], a4);
                    a5 = dot2(hq.h[1], whh[4*k + 1], a5);
                    a6 = dot2(hq.h[2], whh[4*k + 2], a6);
                    a7 = dot2(hq.h[3], whh[4*k + 3], a7);
                }
            }
            float s = ((a0 + a1) + (a2 + a3)) + ((a4 + a5) + (a6 + a7));
            hn = fast_tanh(s + bias);
            ((_Float16*)hb[p ^ 1])[tid] = (_Float16)hn;   // 1 ds_write_b16
            // x-projection of next step fills the barrier shadow
            if (tt != TC - 1) XP(tt + 1, cb);
            __syncthreads();
        }
    }

    // ---- epilogue: out[row] = sigmoid(fc_b + sum_j fc_w[j] * h[j]) ----
    float partial = fw * hn;
    #pragma unroll
    for (int off = 32; off > 0; off >>= 1)
        partial += __shfl_down(partial, off, 64);
    if ((tid & 63) == 0) wred[tid >> 6] = partial;
    __syncthreads();
    if (tid == 0)
        out[row] = fast_sigmoid(fc_b[0] + wred[0] + wred[1]);
}

extern "C" void kernel_launch(void* const* d_in, const int* in_sizes, int n_in,
                              void* d_out, int out_size, void* d_ws, size_t ws_size,
                              hipStream_t stream) {
    const float* x    = (const float*)d_in[0];
    const float* W_ih = (const float*)d_in[1];
    const float* W_hh = (const float*)d_in[2];
    const float* b_ih = (const float*)d_in[3];
    const float* b_hh = (const float*)d_in[4];
    const float* fc_w = (const float*)d_in[5];
    const float* fc_b = (const float*)d_in[6];
    float* out = (float*)d_out;

    rnn_rowwave<<<Bsz, NT, 0, stream>>>(x, W_ih, W_hh, b_ih, b_hh, fc_w, fc_b, out);
}